// Round 4
// baseline (411.568 us; speedup 1.0000x reference)
//
#include <hip/hip_runtime.h>

// OnlineReweightingLoss: N=1048576, C=64, S=8.
// out = sum_i per_sample_i / count[key_i],  key = target*8 + subgroup.
//
// R4 == R3 resubmitted (R3 hit GPUAcquisitionTimeout, never measured).
// rocprof (R1/R2) shows the timed region is dominated by ~2x 1-GiB workspace
// poison fills (~160 us each @6.7 TB/s); our kernels sum to ~30-55 us.
// This structure maximizes memory-level parallelism to pin down the
// kernel-side floor:
//   - lane-per-row: each lane reads its own full 64-float row as 16
//     independent dwordx4 loads (two batches of 8), no shfl chain, no
//     owner-lane divergence, no LDS atomics in the hot loop.
//   - logits[r*64+t] re-read issued EARLY (hits the same lines the row
//     pass fetches -> no extra HBM traffic, latency hidden).
//   - <=64-VGPR target via __launch_bounds__(256,8) -> 32 waves/CU.
// Pass 1 (count): 512-bin LDS histogram -> cnt[512] in ws (2 KB used).
// Plain (cacheable) loads everywhere: logits are ~L3-resident (268 MB vs
// 256 MB L3), which is where the R1 numbers say the win is.

#define NKEYS 512
typedef float v4f __attribute__((ext_vector_type(4)));

__device__ __forceinline__ float esum4(v4f v) {
    return __expf(v.x) + __expf(v.y) + __expf(v.z) + __expf(v.w);
}

// ---- Pass 1: global (target,subgroup) counts -> cnt[512] (pre-zeroed) ----
__global__ __launch_bounds__(256)
void orl_count_kernel(const int* __restrict__ targets,
                      const int* __restrict__ subg,
                      unsigned int* __restrict__ cnt,
                      int n) {
    __shared__ unsigned int lcnt[NKEYS];
    for (int i = threadIdx.x; i < NKEYS; i += 256) lcnt[i] = 0u;
    __syncthreads();

    const int tid = blockIdx.x * 256 + threadIdx.x;
    const int nth = gridDim.x * 256;
    const int n4 = n >> 2;
    for (int i4 = tid; i4 < n4; i4 += nth) {
        const int4 t4 = ((const int4*)targets)[i4];
        const int4 u4 = ((const int4*)subg)[i4];
        atomicAdd(&lcnt[t4.x * 8 + u4.x], 1u);
        atomicAdd(&lcnt[t4.y * 8 + u4.y], 1u);
        atomicAdd(&lcnt[t4.z * 8 + u4.z], 1u);
        atomicAdd(&lcnt[t4.w * 8 + u4.w], 1u);
    }
    for (int i = (n4 << 2) + tid; i < n; i += nth)
        atomicAdd(&lcnt[targets[i] * 8 + subg[i]], 1u);

    __syncthreads();
    for (int i = threadIdx.x; i < NKEYS; i += 256) {
        const unsigned int c = lcnt[i];
        if (c) atomicAdd(&cnt[i], c);
    }
}

// ---- Pass 2: fused loss + weight + global sum, lane-per-row ----
__global__ __launch_bounds__(256, 8)
void orl_main_kernel(const float* __restrict__ logits,
                     const int* __restrict__ targets,
                     const int* __restrict__ subg,
                     const unsigned int* __restrict__ cnt,
                     float* __restrict__ out,
                     int n) {
    __shared__ float lcf[NKEYS];      // counts as exact floats (<= N < 2^24)
    for (int i = threadIdx.x; i < NKEYS; i += 256) lcf[i] = (float)cnt[i];
    __syncthreads();

    const int tid = blockIdx.x * 256 + threadIdx.x;
    const int nth = gridDim.x * 256;

    float acc = 0.0f;
    for (int r = tid; r < n; r += nth) {
        const int t = targets[r];            // coalesced scalar loads
        const int u = subg[r];
        const float* rp = logits + (size_t)r * 64;
        const float xt = rp[t];              // early issue; shares lines with row pass
        const v4f* p = (const v4f*)rp;
        float s = 0.0f;
        // two batches of 8 independent dwordx4 loads (<=64 VGPR budget)
        #pragma unroll
        for (int h = 0; h < 2; ++h) {
            const v4f a0 = p[8*h+0], a1 = p[8*h+1], a2 = p[8*h+2], a3 = p[8*h+3];
            const v4f a4 = p[8*h+4], a5 = p[8*h+5], a6 = p[8*h+6], a7 = p[8*h+7];
            s += esum4(a0) + esum4(a1) + esum4(a2) + esum4(a3)
               + esum4(a4) + esum4(a5) + esum4(a6) + esum4(a7);
        }
        acc += (__logf(s) - xt) / lcf[t * 8 + u];   // exact f32 div, as reference
    }

    // wave reduce, then block reduce, one atomicAdd per block
    #pragma unroll
    for (int m = 1; m < 64; m <<= 1) acc += __shfl_xor(acc, m, 64);
    __shared__ float wsum[4];
    if ((threadIdx.x & 63) == 0) wsum[threadIdx.x >> 6] = acc;
    __syncthreads();
    if (threadIdx.x == 0)
        atomicAdd(out, wsum[0] + wsum[1] + wsum[2] + wsum[3]);
}

extern "C" void kernel_launch(void* const* d_in, const int* in_sizes, int n_in,
                              void* d_out, int out_size, void* d_ws, size_t ws_size,
                              hipStream_t stream) {
    const float* logits  = (const float*)d_in[0];
    const int*   targets = (const int*)d_in[1];
    const int*   subg    = (const int*)d_in[2];
    const int n = in_sizes[1];
    float* out = (float*)d_out;

    unsigned int* cnt = (unsigned int*)d_ws;   // 2 KB of workspace used

    hipMemsetAsync(out, 0, sizeof(float), stream);
    hipMemsetAsync(cnt, 0, NKEYS * sizeof(unsigned int), stream);
    orl_count_kernel<<<512, 256, 0, stream>>>(targets, subg, cnt, n);
    orl_main_kernel<<<2048, 256, 0, stream>>>(logits, targets, subg, cnt, out, n);
}

// Round 5
// 356.232 us; speedup vs baseline: 1.1553x; 1.1553x over previous
//
#include <hip/hip_runtime.h>

// OnlineReweightingLoss: N=1048576, C=64, S=8.
// out = sum_k ( sum_{i in key k} per_sample_i ) / count_k
//
// R5: rocprof arithmetic (R1/R2/R4) pins the timed region at ~320 us of
// harness workspace poison fills (2x 1-GiB @ ~6.7 TB/s) + kernel residuals
// of R1=~33us / R2=~55us / R4=~92us. Best hot loop = R1's: NT logits loads,
// 16 lanes/row, int4 index loads, shfl-xor row reduce, owner-lane LDS bins.
// This round keeps that hot loop BYTE-IDENTICAL and removes everything else:
//   - count pre-pass (8 MB index reads -> global cnt[512], ~3 us)
//   - kernel A bins only lsum (1 LDS atomic/sample, was 2), then the flush
//     divides by the GLOBAL count (512 divs/block) and block-reduces to a
//     single atomicAdd(out) -> no psum/pcnt (2 MB), no reduce kernel.

#define NKEYS 512
#define ABLOCK 512   // kernel A block size (8 waves); must equal NKEYS
typedef float v4f __attribute__((ext_vector_type(4)));

static_assert(ABLOCK == NKEYS, "flush assumes one key per thread");

__device__ __forceinline__ float pick4(v4f v, int j) {
    float r = v.x;
    r = (j == 1) ? v.y : r;
    r = (j == 2) ? v.z : r;
    r = (j == 3) ? v.w : r;
    return r;
}

__device__ __forceinline__ float esum4(v4f v) {
    return __expf(v.x) + __expf(v.y) + __expf(v.z) + __expf(v.w);
}

// ---- Pass 1: global (target,subgroup) counts -> cnt[512] (pre-zeroed) ----
__global__ __launch_bounds__(256)
void orl_count_kernel(const int* __restrict__ targets,
                      const int* __restrict__ subg,
                      unsigned int* __restrict__ cnt,
                      int n) {
    __shared__ unsigned int lcnt[NKEYS];
    for (int i = threadIdx.x; i < NKEYS; i += 256) lcnt[i] = 0u;
    __syncthreads();

    const int tid = blockIdx.x * 256 + threadIdx.x;
    const int nth = gridDim.x * 256;
    const int n4 = n >> 2;
    for (int i4 = tid; i4 < n4; i4 += nth) {
        const int4 t4 = ((const int4*)targets)[i4];
        const int4 u4 = ((const int4*)subg)[i4];
        atomicAdd(&lcnt[t4.x * 8 + u4.x], 1u);
        atomicAdd(&lcnt[t4.y * 8 + u4.y], 1u);
        atomicAdd(&lcnt[t4.z * 8 + u4.z], 1u);
        atomicAdd(&lcnt[t4.w * 8 + u4.w], 1u);
    }
    for (int i = (n4 << 2) + tid; i < n; i += nth)
        atomicAdd(&lcnt[targets[i] * 8 + subg[i]], 1u);

    __syncthreads();
    for (int i = threadIdx.x; i < NKEYS; i += 256) {
        const unsigned int c = lcnt[i];
        if (c) atomicAdd(&cnt[i], c);
    }
}

// ---- Pass 2: R1 hot loop + in-kernel weighted flush ----
__global__ __launch_bounds__(ABLOCK, 4)
void orl_main_kernel(const float* __restrict__ logits,
                     const int* __restrict__ targets,
                     const int* __restrict__ subg,
                     const unsigned int* __restrict__ cnt,
                     float* __restrict__ out,
                     int n) {
    __shared__ float lsum[NKEYS];
    for (int i = threadIdx.x; i < NKEYS; i += ABLOCK) lsum[i] = 0.0f;
    __syncthreads();

    const int lane = threadIdx.x & 63;
    const int q    = lane & 15;        // float4 index within row
    const int g    = lane >> 4;        // 4-row group within wave's 16 rows
    const int wave = (blockIdx.x << 3) | (threadIdx.x >> 6);   // 8 waves/block
    const int nwaves = gridDim.x << 3;

    int base = wave * 16;
    for (; base + 16 <= n; base += nwaves * 16) {
        const int r0 = base + g * 4;   // this lane-group's 4 contiguous rows
        const int4 t4 = *(const int4*)(targets + r0);
        const int4 u4 = *(const int4*)(subg + r0);
        // 4 independent dwordx4 loads, 64-B-line coalesced; nontemporal.
        const float* rowp = logits + (size_t)r0 * 64 + q * 4;
        const v4f v0 = __builtin_nontemporal_load((const v4f*)(rowp));
        const v4f v1 = __builtin_nontemporal_load((const v4f*)(rowp + 64));
        const v4f v2 = __builtin_nontemporal_load((const v4f*)(rowp + 128));
        const v4f v3 = __builtin_nontemporal_load((const v4f*)(rowp + 192));

        float s0 = esum4(v0), s1 = esum4(v1), s2 = esum4(v2), s3 = esum4(v3);
        // xor-reduce over the 16 q-lanes sharing each row
        #pragma unroll
        for (int m = 1; m < 16; m <<= 1) {
            s0 += __shfl_xor(s0, m, 16);
            s1 += __shfl_xor(s1, m, 16);
            s2 += __shfl_xor(s2, m, 16);
            s3 += __shfl_xor(s3, m, 16);
        }
        if ((t4.x >> 2) == q)
            atomicAdd(&lsum[t4.x * 8 + u4.x], __logf(s0) - pick4(v0, t4.x & 3));
        if ((t4.y >> 2) == q)
            atomicAdd(&lsum[t4.y * 8 + u4.y], __logf(s1) - pick4(v1, t4.y & 3));
        if ((t4.z >> 2) == q)
            atomicAdd(&lsum[t4.z * 8 + u4.z], __logf(s2) - pick4(v2, t4.z & 3));
        if ((t4.w >> 2) == q)
            atomicAdd(&lsum[t4.w * 8 + u4.w], __logf(s3) - pick4(v3, t4.w & 3));
    }
    // generic-n tail (not taken for N=1M with this grid)
    for (int o = 0; o < 4; ++o) {
        const int r = base + g * 4 + o;
        if (r < n) {
            const v4f v = *((const v4f*)(logits + (size_t)r * 64) + q);
            const int t = targets[r];
            float s = esum4(v);
            #pragma unroll
            for (int m = 1; m < 16; m <<= 1) s += __shfl_xor(s, m, 16);
            if ((t >> 2) == q)
                atomicAdd(&lsum[t * 8 + subg[r]], __logf(s) - pick4(v, t & 3));
        }
    }

    __syncthreads();
    // Flush: thread k owns key k; divide block-partial sum by GLOBAL count,
    // block-reduce, one atomicAdd(out) per block (512 total).
    float w = 0.0f;
    {
        const unsigned int gc = cnt[threadIdx.x];
        if (gc) w = lsum[threadIdx.x] / (float)gc;   // exact f32 div
    }
    #pragma unroll
    for (int m = 1; m < 64; m <<= 1) w += __shfl_xor(w, m, 64);
    __shared__ float wsum[8];
    if ((threadIdx.x & 63) == 0) wsum[threadIdx.x >> 6] = w;
    __syncthreads();
    if (threadIdx.x == 0) {
        float t = 0.0f;
        #pragma unroll
        for (int i = 0; i < 8; ++i) t += wsum[i];
        atomicAdd(out, t);
    }
}

extern "C" void kernel_launch(void* const* d_in, const int* in_sizes, int n_in,
                              void* d_out, int out_size, void* d_ws, size_t ws_size,
                              hipStream_t stream) {
    const float* logits  = (const float*)d_in[0];
    const int*   targets = (const int*)d_in[1];
    const int*   subg    = (const int*)d_in[2];
    const int n = in_sizes[1];
    float* out = (float*)d_out;

    unsigned int* cnt = (unsigned int*)d_ws;   // 2 KB of workspace used

    hipMemsetAsync(out, 0, sizeof(float), stream);
    hipMemsetAsync(cnt, 0, NKEYS * sizeof(unsigned int), stream);
    orl_count_kernel<<<512, 256, 0, stream>>>(targets, subg, cnt, n);
    orl_main_kernel<<<512, ABLOCK, 0, stream>>>(logits, targets, subg, cnt, out, n);
}